// Round 1
// 179.209 us; speedup vs baseline: 1.0022x; 1.0022x over previous
//
#include <hip/hip_runtime.h>

// Problem constants (match reference setup_inputs)
#define BB 16
#define SS 2048
#define DD 768
#define D4 (DD / 4)   // 192 float4 per row

// Fully fused segment-mean: one wave per output slot (b,w), 4 waves per block.
// seg row is sorted, so segment w is the contiguous run [lower_bound(w),
// lower_bound(w+1)).
//
// v2: the old 11-iteration dependent-load binary search (the longest serial
// memory chain in the kernel) is replaced by a cooperative 64-ary search:
//   round 1: lane i probes srow[32*i]      -> ballot/popcount picks bucket
//   round 2: lanes 0..32 probe the bucket  -> ballot gives exact lower bound
//            AND the run length from the equality mask (covers runs up to the
//            bucket edge; rare spill falls back to the probe loop).
// Dependent chain: ~12 loads -> ~2 loads. Run-sum loop is software-pipelined.
__global__ __launch_bounds__(256) void seg_mean_fused(
    const float* __restrict__ x,
    const int*   __restrict__ seg,
    float*       __restrict__ out) {
    int lane = threadIdx.x & 63;
    int wave = threadIdx.x >> 6;
    int bw   = (blockIdx.x << 2) + wave;      // b*S + w
    int b    = bw >> 11;                       // / SS
    int w    = bw & (SS - 1);
    const int* srow = seg + (b << 11);

    // ---- Round 1: 64 parallel probes at stride 32 (covers all 2048) ----
    int v1 = srow[lane << 5];                  // idx <= 2016, always in range
    int k  = __popcll(__ballot(v1 < w));       // sorted => (v<w) is a prefix; k in [0,64]
    int base2 = (k == 0) ? 0 : ((k - 1) << 5); // lower bound is in [base2, base2+32]

    // ---- Round 2: lanes 0..32 probe [base2, base2+32] ----
    int idx2 = base2 + lane;
    int v2 = 0x7fffffff;                       // acts as +inf: not <w, not ==w
    if (lane < 33 && idx2 < SS) v2 = srow[idx2];
    int k2 = __popcll(__ballot(v2 < w));       // in [0,32]
    int lo = base2 + k2;                       // lower_bound (may be SS)
    unsigned long long meq = __ballot(v2 == w);
    int cwin  = (int)__builtin_ctzll(~(meq >> k2)); // run length visible in window
    int avail = 33 - k2;                            // entries probed at/after lo

    int c;
    if (cwin < avail) {
        c = cwin;                              // run (or emptiness) fully resolved
    } else {
        // run reaches the window edge (rare): keep probing cooperatively
        c = avail;
        int p = base2 + 33;
        for (;;) {
            int idx = p + lane;
            int v   = (idx < SS) ? srow[idx] : -1;
            unsigned long long m  = __ballot(v == w);
            unsigned long long nm = ~m;
            if (nm) { c += (int)__builtin_ctzll(nm); break; }
            c += 64; p += 64;
        }
    }

    float4* outp = (float4*)(out + (size_t)bw * DD);
    if (c == 0) {
        float4 z = make_float4(0.f, 0.f, 0.f, 0.f);
        outp[lane]       = z;
        outp[lane + 64]  = z;
        outp[lane + 128] = z;
        return;
    }

    const float4* xp = (const float4*)(x + ((size_t)b * SS + (size_t)lo) * DD);
    float4 a0 = xp[lane];
    float4 a1 = xp[lane + 64];
    float4 a2 = xp[lane + 128];
    if (c > 1) {
        // software-pipelined: issue row j+1's loads before accumulating row j
        const float4* xr = xp + D4;
        float4 r0 = xr[lane], r1 = xr[lane + 64], r2 = xr[lane + 128];
        for (int j = 2; j < c; ++j) {
            const float4* xn = xp + (size_t)j * D4;
            float4 t0 = xn[lane], t1 = xn[lane + 64], t2 = xn[lane + 128];
            a0.x += r0.x; a0.y += r0.y; a0.z += r0.z; a0.w += r0.w;
            a1.x += r1.x; a1.y += r1.y; a1.z += r1.z; a1.w += r1.w;
            a2.x += r2.x; a2.y += r2.y; a2.z += r2.z; a2.w += r2.w;
            r0 = t0; r1 = t1; r2 = t2;
        }
        a0.x += r0.x; a0.y += r0.y; a0.z += r0.z; a0.w += r0.w;
        a1.x += r1.x; a1.y += r1.y; a1.z += r1.z; a1.w += r1.w;
        a2.x += r2.x; a2.y += r2.y; a2.z += r2.z; a2.w += r2.w;
    }
    float inv = 1.0f / (float)c;
    a0.x *= inv; a0.y *= inv; a0.z *= inv; a0.w *= inv;
    a1.x *= inv; a1.y *= inv; a1.z *= inv; a1.w *= inv;
    a2.x *= inv; a2.y *= inv; a2.z *= inv; a2.w *= inv;
    outp[lane]       = a0;
    outp[lane + 64]  = a1;
    outp[lane + 128] = a2;
}

extern "C" void kernel_launch(void* const* d_in, const int* in_sizes, int n_in,
                              void* d_out, int out_size, void* d_ws, size_t ws_size,
                              hipStream_t stream) {
    const float* x   = (const float*)d_in[0];   // [B,S,D] fp32
    const int*   seg = (const int*)d_in[1];     // [B,S] int32
    float* out = (float*)d_out;                 // [B,S,D] fp32

    // 4 output slots per 256-thread block
    int nBlocks = (BB * SS) / 4;                // 8192
    seg_mean_fused<<<nBlocks, 256, 0, stream>>>(x, seg, out);
}